// Round 10
// baseline (110.851 us; speedup 1.0000x reference)
//
#include <hip/hip_runtime.h>

// src (B,C,D,H,W) f32, flow (B,3,D,H,W) f32, C==1
constexpr int B  = 2;
constexpr int D  = 160;
constexpr int H  = 192;
constexpr int W  = 224;
constexpr int HW = H * W;        // 43008
constexpr int N  = D * HW;       // 6,881,280 per volume

// Block tile 32x * 8y * 8z = 2048 voxels, 256 threads, 8 voxels/thread.
// LDS slab (f16!) = tile + halo 4 each side: 40*16*16 halfs = 20 KiB
// -> 8 blocks/CU co-resident (100% wave occupancy cap).
constexpr int TX = 32, TY = 8, TZ = 8;
constexpr int HALO = 4;
constexpr int SLX = TX + 2 * HALO;   // 40
constexpr int SLY = TY + 2 * HALO;   // 16
constexpr int SLZ = TZ + 2 * HALO;   // 16
constexpr int SLAB = SLX * SLY * SLZ;        // 10240 halfs = 20480 B
constexpr int GX = W / TX;   // 7
constexpr int GY = H / TY;   // 24
constexpr int GZ = D / TZ;   // 20
constexpr int NBLOCKS = GX * GY * GZ * B;    // 6720

typedef float f2 __attribute__((ext_vector_type(2)));
typedef __fp16 h2 __attribute__((ext_vector_type(2)));
struct __attribute__((packed, aligned(4))) f2u { f2 v; };

__global__ __launch_bounds__(256, 8) void st3d_warp_v7(
    const float* __restrict__ src,
    const float* __restrict__ flow,
    float* __restrict__ out)
{
    __shared__ __align__(16) __fp16 lds[SLAB];

    const int tid = threadIdx.x;
    int tmp = blockIdx.x;
    const int bx = tmp % GX; tmp /= GX;
    const int by = tmp % GY; tmp /= GY;
    const int bz = tmp % GZ;
    const int b  = tmp / GZ;

    const int xb = bx * TX, yb = by * TY, zb = bz * TZ;
    const int xlo = xb - HALO, ylo = yb - HALO, zlo = zb - HALO;

    const int x = xb + (tid & 31);
    const int y = yb + (tid >> 5);           // [0,8)

    const float* fl = flow + (size_t)b * 3 * N;
    const float* sb = src  + (size_t)b * N;   // C == 1

    // ---- flow preload (24 independent coalesced loads) ----
    float fzv[TZ], fyv[TZ], fxv[TZ];
    const int n0 = zb * HW + y * W + x;
#pragma unroll
    for (int j = 0; j < TZ; ++j) {
        int n = n0 + j * HW;
        fzv[j] = fl[n];
        fyv[j] = fl[N + n];
        fxv[j] = fl[2 * N + n];
    }

    // ---- stage slab as f16: 2560 float4 reads, 10 per thread ----
    // OOB halo cells get garbage values (flat-clamped address, memory-safe):
    // provably never read, since read indices are pre-clamped into the volume
    // and every in-volume coordinate in the slab is staged from its true row.
#pragma unroll
    for (int k = 0; k < SLAB / 4 / 256; ++k) {   // 10
        int s4  = k * 256 + tid;                 // [0,2560)
        int q   = s4 / 10;                       // slab row (sz*16+sy), [0,256)
        int sx4 = s4 - q * 10;
        int sz  = q >> 4;
        int sy  = q & 15;
        int flat = (zlo + sz) * HW + (ylo + sy) * W + (xlo + sx4 * 4);
        flat = min(max(flat, 0), N - 4);         // safety only
        float4 v = *reinterpret_cast<const float4*>(sb + flat);
        h2 h01 = __builtin_amdgcn_cvt_pkrtz(v.x, v.y);
        h2 h23 = __builtin_amdgcn_cvt_pkrtz(v.z, v.w);
        float2 st;
        st.x = __builtin_bit_cast(float, h01);
        st.y = __builtin_bit_cast(float, h23);
        *reinterpret_cast<float2*>(&lds[q * SLX + sx4 * 4]) = st;  // 8B aligned
    }
    __syncthreads();

    // ---- per-voxel compute: 8 z-planes per thread ----
#pragma unroll
    for (int j = 0; j < TZ; ++j) {
        int z = zb + j;
        float cz = (float)z + fzv[j];
        float cy = (float)y + fyv[j];
        float cx = (float)x + fxv[j];

        float fz0 = floorf(cz); int z0 = (int)fz0; float fz = cz - fz0;
        float fy0 = floorf(cy); int y0 = (int)fy0; float fy = cy - fy0;
        float fx0 = floorf(cx); int x0 = (int)fx0; float fx = cx - fx0;
        int z1 = z0 + 1, y1 = y0 + 1, x1 = x0 + 1;

        float wz0 = (1.0f - fz) * ((z0 >= 0 && z0 < D) ? 1.0f : 0.0f);
        float wz1 = fz          * ((z1 >= 0 && z1 < D) ? 1.0f : 0.0f);
        float wy0 = (1.0f - fy) * ((y0 >= 0 && y0 < H) ? 1.0f : 0.0f);
        float wy1 = fy          * ((y1 >= 0 && y1 < H) ? 1.0f : 0.0f);
        float wx0 = (1.0f - fx) * ((x0 >= 0 && x0 < W) ? 1.0f : 0.0f);
        float wx1 = fx          * ((x1 >= 0 && x1 < W) ? 1.0f : 0.0f);

        // x-pair base; wrong-slot cases carry weight 0 (verified per-case).
        int  xp   = min(max(x0, 0), W - 2);
        bool sel0 = (x0 == xp);
        // weight swap: f = p0*wa + p1*wb covers all 3 edge cases exactly
        // (sel0: wa=wx0,wb=wx1; x0==-1: p1 is the valid col-0 sample and
        //  wx0 is its weight -> wa=wx1(=0 when both OOB),wb=wx0; x0==W-1:
        //  wa=wx1=0, wb=wx0 picks p1=col W-1.)
        float wa = sel0 ? wx0 : wx1;
        float wb = sel0 ? wx1 : wx0;

        int zc0 = min(max(z0, 0), D - 1), zc1 = min(max(z1, 0), D - 1);
        int yc0 = min(max(y0, 0), H - 1), yc1 = min(max(y1, 0), H - 1);

        int lz0 = zc0 - zlo, ly0 = yc0 - ylo, lx = xp - xlo;
        bool in_slab = ((unsigned)lz0 < (unsigned)(SLZ - 1))
                     & ((unsigned)ly0 < (unsigned)(SLY - 1))
                     & ((unsigned)lx  < (unsigned)(SLX - 1));

        float p00x, p00y, p01x, p01y, p10x, p10y, p11x, p11y;
        if (in_slab) {
            int lz1 = zc1 - zlo, ly1 = yc1 - ylo;   // <= lz0+1 / ly0+1, in slab
            int e00 = (lz0 * SLY + ly0) * SLX + lx;
            int e01 = (lz0 * SLY + ly1) * SLX + lx;
            int e10 = (lz1 * SLY + ly0) * SLX + lx;
            int e11 = (lz1 * SLY + ly1) * SLX + lx;
            p00x = (float)lds[e00]; p00y = (float)lds[e00 + 1];
            p01x = (float)lds[e01]; p01y = (float)lds[e01 + 1];
            p10x = (float)lds[e10]; p10y = (float)lds[e10 + 1];
            p11x = (float)lds[e11]; p11y = (float)lds[e11 + 1];
        } else {
            // rare (|flow| >= ~4): direct global f32 gather
            f2 t00 = ((const f2u*)(sb + zc0 * HW + yc0 * W + xp))->v;
            f2 t01 = ((const f2u*)(sb + zc0 * HW + yc1 * W + xp))->v;
            f2 t10 = ((const f2u*)(sb + zc1 * HW + yc0 * W + xp))->v;
            f2 t11 = ((const f2u*)(sb + zc1 * HW + yc1 * W + xp))->v;
            p00x = t00.x; p00y = t00.y;
            p01x = t01.x; p01y = t01.y;
            p10x = t10.x; p10y = t10.y;
            p11x = t11.x; p11y = t11.y;
        }

        float f00 = p00x * wa + p00y * wb;
        float f01 = p01x * wa + p01y * wb;
        float f10 = p10x * wa + p10y * wb;
        float f11 = p11x * wa + p11y * wb;

        float acc = wz0 * (wy0 * f00 + wy1 * f01)
                  + wz1 * (wy0 * f10 + wy1 * f11);

        out[(size_t)b * N + z * HW + y * W + x] = acc;
    }
}

extern "C" void kernel_launch(void* const* d_in, const int* in_sizes, int n_in,
                              void* d_out, int out_size, void* d_ws, size_t ws_size,
                              hipStream_t stream)
{
    const float* src  = (const float*)d_in[0];
    const float* flow = (const float*)d_in[1];
    float* out = (float*)d_out;

    st3d_warp_v7<<<NBLOCKS, 256, 0, stream>>>(src, flow, out);
}

// Round 11
// 83.709 us; speedup vs baseline: 1.3242x; 1.3242x over previous
//
#include <hip/hip_runtime.h>

// src (B,C,D,H,W) f32, flow (B,3,D,H,W) f32, C==1
constexpr int B  = 2;
constexpr int D  = 160;
constexpr int H  = 192;
constexpr int W  = 224;
constexpr int HW = H * W;        // 43008
constexpr int N  = D * HW;       // 6,881,280 per volume

// Block tile: 32x * 8y * 2z = 512 voxels; 256 threads, 2 z-voxels/thread.
// Wave footprint per memory instruction: 32x * 2y (v5's proven layout).
constexpr int GX = W / 32;       // 7
constexpr int GY = H / 8;        // 24
constexpr int GZ = D / 2;        // 80
constexpr int NBLOCKS = GX * GY * GZ * B;    // 26880

typedef float f2 __attribute__((ext_vector_type(2)));
// 8-byte gather with 4-byte alignment guarantee (single global_load_dwordx2)
struct __attribute__((packed, aligned(4))) f2u { f2 v; };

__global__ __launch_bounds__(256, 8) void st3d_warp_v8(
    const float* __restrict__ src,
    const float* __restrict__ flow,
    float* __restrict__ out)
{
    const int tid = threadIdx.x;
    int tmp = blockIdx.x;
    const int bx = tmp % GX; tmp /= GX;
    const int by = tmp % GY; tmp /= GY;
    const int bz = tmp % GZ;
    const int b  = tmp / GZ;

    const int x = bx * 32 + (tid & 31);
    const int y = by * 8  + (tid >> 5);     // [0,8)
    const int zb = bz * 2;

    const float* fl = flow + (size_t)b * 3 * N;
    const float* sb = src  + (size_t)b * N;   // C == 1

    // ---- phase A: all 6 flow loads issued together (coalesced) ----
    const int n0 = zb * HW + y * W + x;
    float dz0 = fl[n0],          dz1 = fl[n0 + HW];
    float dy0 = fl[N + n0],      dy1 = fl[N + n0 + HW];
    float dx0 = fl[2*N + n0],    dx1 = fl[2*N + n0 + HW];

    // ---- phase B: per-voxel indices/weights, then 8 independent gathers ----
    float wz0[2], wz1[2], wy0[2], wy1[2], wa[2], wb[2];
    const float* ap[2][4];
#pragma unroll
    for (int j = 0; j < 2; ++j) {
        float cz = (float)(zb + j) + (j ? dz1 : dz0);
        float cy = (float)y        + (j ? dy1 : dy0);
        float cx = (float)x        + (j ? dx1 : dx0);

        float fz0 = floorf(cz); int z0 = (int)fz0; float fz = cz - fz0;
        float fy0 = floorf(cy); int y0 = (int)fy0; float fy = cy - fy0;
        float fx0 = floorf(cx); int x0 = (int)fx0; float fx = cx - fx0;
        int z1 = z0 + 1, y1 = y0 + 1, x1 = x0 + 1;

        wz0[j] = (1.0f - fz) * ((z0 >= 0 && z0 < D) ? 1.0f : 0.0f);
        wz1[j] = fz          * ((z1 >= 0 && z1 < D) ? 1.0f : 0.0f);
        wy0[j] = (1.0f - fy) * ((y0 >= 0 && y0 < H) ? 1.0f : 0.0f);
        wy1[j] = fy          * ((y1 >= 0 && y1 < H) ? 1.0f : 0.0f);
        float wx0 = (1.0f - fx) * ((x0 >= 0 && x0 < W) ? 1.0f : 0.0f);
        float wx1 = fx          * ((x1 >= 0 && x1 < W) ? 1.0f : 0.0f);

        // x-pair base; wrong-slot cases carry weight 0 (verified per-case):
        //   x0 in [0,W-2]: wa=wx0 (slot p.x), wb=wx1 (slot p.y)
        //   x0 == -1     : wa=wx1(=0 if both OOB), wb=wx0 -> picks col 0 in p.y
        //   x0 == W-1    : wa=wx1(=0), wb=wx0 -> picks col W-1... wait p.x=W-2?
        //   (sel0 false only when x0>xp i.e. x0==W-1: pair=(W-2,W-1); valid
        //    corner x0=W-1 sits in p.x? No: xp=W-2, p.x=src[W-2]=x-corner0?
        //    x0==W-1 -> corner x0 at col W-1 = p.y, corner x1=W OOB (wx1 dead).
        //    wa applies to p.x (col W-2, belongs to NO corner -> must be 0 =
        //    wx1 since x1 OOB), wb=wx0 applies to p.y (col W-1 = corner x0). ok)
        int  xp   = min(max(x0, 0), W - 2);
        bool sel0 = (x0 == xp);
        wa[j] = sel0 ? wx0 : wx1;
        wb[j] = sel0 ? wx1 : wx0;

        int zc0 = min(max(z0, 0), D - 1), zc1 = min(max(z1, 0), D - 1);
        int yc0 = min(max(y0, 0), H - 1), yc1 = min(max(y1, 0), H - 1);

        ap[j][0] = sb + zc0 * HW + yc0 * W + xp;
        ap[j][1] = sb + zc0 * HW + yc1 * W + xp;
        ap[j][2] = sb + zc1 * HW + yc0 * W + xp;
        ap[j][3] = sb + zc1 * HW + yc1 * W + xp;
    }

    // 8 independent 8B gathers — all in flight before any use
    f2 p00 = ((const f2u*)ap[0][0])->v;
    f2 p01 = ((const f2u*)ap[0][1])->v;
    f2 p02 = ((const f2u*)ap[0][2])->v;
    f2 p03 = ((const f2u*)ap[0][3])->v;
    f2 p10 = ((const f2u*)ap[1][0])->v;
    f2 p11 = ((const f2u*)ap[1][1])->v;
    f2 p12 = ((const f2u*)ap[1][2])->v;
    f2 p13 = ((const f2u*)ap[1][3])->v;

    // ---- phase C: combine + coalesced stores ----
    float f00 = p00.x * wa[0] + p00.y * wb[0];
    float f01 = p01.x * wa[0] + p01.y * wb[0];
    float f02 = p02.x * wa[0] + p02.y * wb[0];
    float f03 = p03.x * wa[0] + p03.y * wb[0];
    float acc0 = wz0[0] * (wy0[0] * f00 + wy1[0] * f01)
               + wz1[0] * (wy0[0] * f02 + wy1[0] * f03);

    float f10 = p10.x * wa[1] + p10.y * wb[1];
    float f11 = p11.x * wa[1] + p11.y * wb[1];
    float f12 = p12.x * wa[1] + p12.y * wb[1];
    float f13 = p13.x * wa[1] + p13.y * wb[1];
    float acc1 = wz0[1] * (wy0[1] * f10 + wy1[1] * f11)
               + wz1[1] * (wy0[1] * f12 + wy1[1] * f13);

    out[(size_t)b * N + n0]      = acc0;
    out[(size_t)b * N + n0 + HW] = acc1;
}

extern "C" void kernel_launch(void* const* d_in, const int* in_sizes, int n_in,
                              void* d_out, int out_size, void* d_ws, size_t ws_size,
                              hipStream_t stream)
{
    const float* src  = (const float*)d_in[0];
    const float* flow = (const float*)d_in[1];
    float* out = (float*)d_out;

    st3d_warp_v8<<<NBLOCKS, 256, 0, stream>>>(src, flow, out);
}